// Round 5
// baseline (181.881 us; speedup 1.0000x reference)
//
#include <hip/hip_runtime.h>
#include <hip/hip_bf16.h>
#include <stdint.h>
#include <math.h>

#define NN 8192
#define DIN 512
#define HH 256
#define EE 262144
#define CAP 96
#define LN_EPS 1e-5f

typedef __attribute__((ext_vector_type(8))) short bf16x8;
typedef __attribute__((ext_vector_type(4))) short s16x4;
typedef __attribute__((ext_vector_type(4))) float f32x4;
typedef __attribute__((ext_vector_type(2))) float f32x2;

#if defined(__has_builtin)
#if __has_builtin(__builtin_amdgcn_cvt_pk_f32_fp8) && __has_builtin(__builtin_amdgcn_cvt_pk_fp8_f32)
#define HAVE_FP8_CVT 1
#endif
#endif

__device__ __forceinline__ short f2bf_bits(float x) {
    __hip_bfloat16 b = __float2bfloat16(x);
    return __builtin_bit_cast(short, b);
}
__device__ __forceinline__ float bf2f(short s) {
    uint32_t u = ((uint32_t)(uint16_t)s) << 16;
    return __builtin_bit_cast(float, u);
}
__device__ __forceinline__ void load16_lds(const void* g, void* l) {
    __builtin_amdgcn_global_load_lds((const __attribute__((address_space(1))) uint32_t*)g,
                                     (__attribute__((address_space(3))) uint32_t*)l, 16, 0, 0);
}

// ---- fp8 e4m3 (OCP) encode/decode: HW cvt on gfx950, software fallback otherwise ----
__device__ __forceinline__ uint8_t f2fp8(float x) {
#ifdef HAVE_FP8_CVT
    uint32_t p = __builtin_amdgcn_cvt_pk_fp8_f32(x, 0.f, 0u, false);
    return (uint8_t)(p & 0xFF);
#else
    uint8_t s = (x < 0.f) ? 0x80 : 0;
    float a = fabsf(x);
    if (!(a == a)) return 0x7F;
    if (a >= 448.f) return s | 0x7E;
    if (a < 0.0009765625f) return s;
    int e; float mf = frexpf(a, &e);
    int E = e + 6;
    if (E <= 0) { int q = (int)(a * 512.f + 0.5f); if (q >= 8) return s | 0x08; return s | (uint8_t)q; }
    int q = (int)(mf * 16.f + 0.5f);
    if (q >= 16) { q = 8; E++; }
    if (E > 15 || (E == 15 && q - 8 > 6)) return s | 0x7E;
    return s | (uint8_t)((E << 3) | (q - 8));
#endif
}
__device__ __forceinline__ void fp8x4_to_f32(uint32_t w, float* f) {
#ifdef HAVE_FP8_CVT
    f32x2 a = __builtin_amdgcn_cvt_pk_f32_fp8(w, false);
    f32x2 b = __builtin_amdgcn_cvt_pk_f32_fp8(w, true);
    f[0] = a[0]; f[1] = a[1]; f[2] = b[0]; f[3] = b[1];
#else
#pragma unroll
    for (int i = 0; i < 4; i++) {
        uint8_t bb = (w >> (8 * i)) & 0xFF;
        int s = bb >> 7, e = (bb >> 3) & 15, m = bb & 7;
        float v = e ? ldexpf((float)(8 + m), e - 10) : ldexpf((float)m, -9);
        f[i] = s ? -v : v;
    }
#endif
}

// ---------------- prep: zero accumulators/cnt/emb, convert W_in/W_gat/X to bf16 ----------------
#define NW1 (HH * DIN)
#define NW2 (2 * HH * HH)
#define NX (NN * DIN)
#define ZCOUNT (2 * (2 * NN + HH) + NN)   // s1/s2/St x2 layers + cnt
__global__ __launch_bounds__(256) void prep(const float* __restrict__ W_in, __hip_bfloat16* __restrict__ Wb_in,
                                            const float* __restrict__ W_gat, __hip_bfloat16* __restrict__ Wgb,
                                            const float* __restrict__ X, __hip_bfloat16* __restrict__ Xb,
                                            float* __restrict__ zbase, float* __restrict__ emb) {
    int gtid = blockIdx.x * 256 + threadIdx.x;
    if (gtid < ZCOUNT) ((int*)zbase)[gtid] = 0;
    if (gtid < HH) emb[gtid] = 0.f;
    int q = gtid * 4;
    const float* x;
    __hip_bfloat16* y;
    int b;
    if (q < NW1) { x = W_in; y = Wb_in; b = q; }
    else if (q < NW1 + NW2) { x = W_gat; y = Wgb; b = q - NW1; }
    else if (q < NW1 + NW2 + NX) { x = X; y = Xb; b = q - NW1 - NW2; }
    else return;
    float4 v = *(const float4*)(x + b);
    y[b + 0] = __float2bfloat16(v.x);
    y[b + 1] = __float2bfloat16(v.y);
    y[b + 2] = __float2bfloat16(v.z);
    y[b + 3] = __float2bfloat16(v.w);
}

// ---------------- bucketed adjacency fill, 2 edges/thread ----------------
__global__ void fill_buckets(const int* __restrict__ src, const int* __restrict__ tgt,
                             int* __restrict__ cnt, int* __restrict__ buck) {
    int k = (blockIdx.x * 256 + threadIdx.x) * 2;
    if (k < EE) {
        int2 sv = *(const int2*)(src + k);
        int2 tv = *(const int2*)(tgt + k);
        int p = atomicAdd(&cnt[sv.x], 1);
        if (p < CAP) buck[sv.x * CAP + p] = tv.x;
        p = atomicAdd(&cnt[sv.y], 1);
        if (p < CAP) buck[sv.y * CAP + p] = tv.y;
    }
}

// ---------------- bf16 GEMM + bias: C_bf16 = A @ B^T + bias ----------------
__global__ __launch_bounds__(256) void gemm_bb_bias(const __hip_bfloat16* __restrict__ A,
                                                    const __hip_bfloat16* __restrict__ B,
                                                    const float* __restrict__ bias,
                                                    __hip_bfloat16* __restrict__ Cb,
                                                    int Nc, int K) {
    __shared__ __hip_bfloat16 As[64 * 32];
    __shared__ __hip_bfloat16 Bs[64 * 32];
    const int tid = threadIdx.x;
    const int row0 = blockIdx.y * 64, col0 = blockIdx.x * 64;
    const int w = tid >> 6, l = tid & 63;
    const int quad = l >> 4, r = l & 15;
    const int mh = (w & 1) * 32, nh = (w >> 1) * 32;
    f32x4 acc[2][2] = {};

    const int srow = tid >> 2, scol = (tid & 3) * 8;
    const __hip_bfloat16* gA = A + (size_t)(row0 + srow) * K + scol;
    const __hip_bfloat16* gB = B + (size_t)(col0 + srow) * K + scol;
    __hip_bfloat16* lA = &As[tid * 8];
    __hip_bfloat16* lB = &Bs[tid * 8];

    for (int k0 = 0; k0 < K; k0 += 32) {
        load16_lds(gA + k0, lA);
        load16_lds(gB + k0, lB);
        __syncthreads();
        bf16x8 aF[2], bF[2];
#pragma unroll
        for (int mi = 0; mi < 2; mi++)
            aF[mi] = *(const bf16x8*)&As[(mh + mi * 16 + r) * 32 + quad * 8];
#pragma unroll
        for (int ni = 0; ni < 2; ni++)
            bF[ni] = *(const bf16x8*)&Bs[(nh + ni * 16 + r) * 32 + quad * 8];
#pragma unroll
        for (int mi = 0; mi < 2; mi++)
#pragma unroll
            for (int ni = 0; ni < 2; ni++)
                acc[mi][ni] = __builtin_amdgcn_mfma_f32_16x16x32_bf16(aF[mi], bF[ni], acc[mi][ni], 0, 0, 0);
        __syncthreads();
    }

#pragma unroll
    for (int mi = 0; mi < 2; mi++)
#pragma unroll
        for (int ni = 0; ni < 2; ni++) {
            int gcol = col0 + nh + ni * 16 + r;
            float bv = bias[gcol];
#pragma unroll
            for (int reg = 0; reg < 4; reg++) {
                int grow = row0 + mh + mi * 16 + quad * 4 + reg;
                Cb[(size_t)grow * Nc + gcol] = __float2bfloat16(acc[mi][ni][reg] + bv);
            }
        }
}

// ---------------- layer GEMM + fused score epilogue; C stored as fp8 e4m3 ----------------
__global__ __launch_bounds__(256) void gemm_bb_score(const __hip_bfloat16* __restrict__ A,
                                                     const __hip_bfloat16* __restrict__ B,
                                                     uint8_t* __restrict__ C8,
                                                     const float* __restrict__ ag1,
                                                     const float* __restrict__ ag2,
                                                     float* __restrict__ s1, float* __restrict__ s2,
                                                     float* __restrict__ St,
                                                     int Nc, int K) {
    __shared__ __hip_bfloat16 As[64 * 32];
    __shared__ __hip_bfloat16 Bs[64 * 32];
    const int tid = threadIdx.x;
    const int row0 = blockIdx.y * 64, col0 = blockIdx.x * 64;
    const int w = tid >> 6, l = tid & 63;
    const int quad = l >> 4, r = l & 15;
    const int mh = (w & 1) * 32, nh = (w >> 1) * 32;
    f32x4 acc[2][2] = {};

    const int srow = tid >> 2, scol = (tid & 3) * 8;
    const __hip_bfloat16* gA = A + (size_t)(row0 + srow) * K + scol;
    const __hip_bfloat16* gB = B + (size_t)(col0 + srow) * K + scol;
    __hip_bfloat16* lA = &As[tid * 8];
    __hip_bfloat16* lB = &Bs[tid * 8];

    for (int k0 = 0; k0 < K; k0 += 32) {
        load16_lds(gA + k0, lA);
        load16_lds(gB + k0, lB);
        __syncthreads();
        bf16x8 aF[2], bF[2];
#pragma unroll
        for (int mi = 0; mi < 2; mi++)
            aF[mi] = *(const bf16x8*)&As[(mh + mi * 16 + r) * 32 + quad * 8];
#pragma unroll
        for (int ni = 0; ni < 2; ni++)
            bF[ni] = *(const bf16x8*)&Bs[(nh + ni * 16 + r) * 32 + quad * 8];
#pragma unroll
        for (int mi = 0; mi < 2; mi++)
#pragma unroll
            for (int ni = 0; ni < 2; ni++)
                acc[mi][ni] = __builtin_amdgcn_mfma_f32_16x16x32_bf16(aF[mi], bF[ni], acc[mi][ni], 0, 0, 0);
        __syncthreads();
    }

#pragma unroll
    for (int mi = 0; mi < 2; mi++)
#pragma unroll
        for (int ni = 0; ni < 2; ni++) {
            int gcol = col0 + nh + ni * 16 + r;
#pragma unroll
            for (int reg = 0; reg < 4; reg++) {
                int grow = row0 + mh + mi * 16 + quad * 4 + reg;
                C8[(size_t)grow * Nc + gcol] = f2fp8(acc[mi][ni][reg]);
            }
        }

    float a1v[2], a2v[2];
#pragma unroll
    for (int ni = 0; ni < 2; ni++) {
        int gcol = col0 + nh + ni * 16 + r;
        a1v[ni] = ag1[gcol];
        a2v[ni] = ag2[gcol];
    }
#pragma unroll
    for (int mi = 0; mi < 2; mi++)
#pragma unroll
        for (int reg = 0; reg < 4; reg++) {
            float p1 = acc[mi][0][reg] * a1v[0] + acc[mi][1][reg] * a1v[1];
            float p2 = acc[mi][0][reg] * a2v[0] + acc[mi][1][reg] * a2v[1];
#pragma unroll
            for (int off = 1; off <= 8; off <<= 1) {
                p1 += __shfl_xor(p1, off);
                p2 += __shfl_xor(p2, off);
            }
            if (r == 0) {
                int grow = row0 + mh + mi * 16 + quad * 4 + reg;
                atomicAdd(&s1[grow], p1);
                atomicAdd(&s2[grow], p2);
            }
        }
#pragma unroll
    for (int ni = 0; ni < 2; ni++) {
        float pS = 0.f;
#pragma unroll
        for (int mi = 0; mi < 2; mi++)
#pragma unroll
            for (int reg = 0; reg < 4; reg++) pS += acc[mi][ni][reg];
        pS += __shfl_xor(pS, 16);
        pS += __shfl_xor(pS, 32);
        if (quad == 0) atomicAdd(&St[col0 + nh + ni * 16 + r], pS);
    }
}

// ---------------- wave-per-4-rows GAT: interleaved gathers for 4x wave-level MLP ----------------
// lane = 64 lanes; half = lane>>5 covers even/odd edges; lane owns channels 8*(lane&31)..+7.
// Each wave processes rows ibase..ibase+3 with interleaved prologue chains and gathers
// (4 pairs x 4 rows = 16 independent loads in flight per step).
__global__ __launch_bounds__(256) void gat_row(const __hip_bfloat16* __restrict__ hprev,
                                               const uint8_t* __restrict__ hw8,
                                               const int* __restrict__ cnt, const int* __restrict__ buck,
                                               const float* __restrict__ s1, const float* __restrict__ s2,
                                               const float* __restrict__ St,
                                               const float* __restrict__ lng, const float* __restrict__ lnb,
                                               const float* __restrict__ W_pool, const float* __restrict__ b_pool,
                                               float* __restrict__ houtf, __hip_bfloat16* __restrict__ houtb,
                                               float* __restrict__ gate, int last) {
    const int wv = threadIdx.x >> 6, lane = threadIdx.x & 63;
    const int half = lane >> 5, sl = lane & 31;
    const int ibase = blockIdx.x * 16 + wv * 4;

    int4 cvec = *(const int4*)(cnt + ibase);
    int deg[4] = { min(cvec.x, CAP), min(cvec.y, CAP), min(cvec.z, CAP), min(cvec.w, CAP) };
    float4 s1q = *(const float4*)(s1 + ibase);
    float s1v[4] = { s1q.x, s1q.y, s1q.z, s1q.w };

    float u[4][8] = {};
    float lsum[4] = { 0.f, 0.f, 0.f, 0.f };
    const int maxdeg = max(max(deg[0], deg[1]), max(deg[2], deg[3]));

    for (int kb = 0; kb < maxdeg; kb += 64) {
        const int k = kb + lane;
        int ck[4];
        float wk[4];
        // interleaved prologue: 4 independent buck loads, then 4 independent s2 gathers
#pragma unroll
        for (int rr = 0; rr < 4; rr++)
            ck[rr] = (k < deg[rr]) ? buck[(ibase + rr) * CAP + k] : -1;
#pragma unroll
        for (int rr = 0; rr < 4; rr++) {
            float wv_ = 0.f;
            if (ck[rr] >= 0) {
                float e = s1v[rr] + s2[ck[rr]];
                e = e > 0.f ? e : 0.2f * e;
                wv_ = __expf(e) - 1.f;
            } else ck[rr] = 0;
            wk[rr] = wv_;
            lsum[rr] += wv_;
        }
        const int nb = min(64, maxdeg - kb);
        const int npair = (nb + 1) >> 1;
        for (int jj = 0; jj < npair; jj += 4) {
            int cj[4][4];
            float wj[4][4];
#pragma unroll
            for (int p = 0; p < 4; p++) {
                int e2 = 2 * (jj + p) + half;   // <= 63 always
#pragma unroll
                for (int rr = 0; rr < 4; rr++) {
                    cj[p][rr] = __shfl(ck[rr], e2);
                    wj[p][rr] = __shfl(wk[rr], e2);
                }
            }
            uint2 hv[4][4];
#pragma unroll
            for (int p = 0; p < 4; p++)
#pragma unroll
                for (int rr = 0; rr < 4; rr++)
                    hv[p][rr] = *(const uint2*)(hw8 + (size_t)cj[p][rr] * HH + 8 * sl);
#pragma unroll
            for (int p = 0; p < 4; p++)
#pragma unroll
                for (int rr = 0; rr < 4; rr++) {
                    float f[8];
                    fp8x4_to_f32(hv[p][rr].x, f);
                    fp8x4_to_f32(hv[p][rr].y, f + 4);
#pragma unroll
                    for (int q = 0; q < 8; q++) u[rr][q] += wj[p][rr] * f[q];
                }
        }
    }

    // hoisted channel-wise constants (same for all 4 rows)
    float4 Sa = *(const float4*)(St + 8 * sl);
    float4 Sb = *(const float4*)(St + 8 * sl + 4);
    float Sts[8] = { Sa.x, Sa.y, Sa.z, Sa.w, Sb.x, Sb.y, Sb.z, Sb.w };
    float4 ga = *(const float4*)(lng + 8 * sl);
    float4 gb = *(const float4*)(lng + 8 * sl + 4);
    float4 ba = *(const float4*)(lnb + 8 * sl);
    float4 bb = *(const float4*)(lnb + 8 * sl + 4);
    float gg[8] = { ga.x, ga.y, ga.z, ga.w, gb.x, gb.y, gb.z, gb.w };
    float bv[8] = { ba.x, ba.y, ba.z, ba.w, bb.x, bb.y, bb.z, bb.w };
    float wp[8];
    float bp = 0.f;
    if (last) {
        float4 wa = *(const float4*)(W_pool + 8 * sl);
        float4 wb = *(const float4*)(W_pool + 8 * sl + 4);
        wp[0] = wa.x; wp[1] = wa.y; wp[2] = wa.z; wp[3] = wa.w;
        wp[4] = wb.x; wp[5] = wb.y; wp[6] = wb.z; wp[7] = wb.w;
        bp = b_pool[0];
    }
    const int co = 8 * sl + 4 * half;

#pragma unroll
    for (int rr = 0; rr < 4; rr++) {
        const int i = ibase + rr;
        // combine even/odd halves; full-wave lsum
        float uu[8];
#pragma unroll
        for (int q = 0; q < 8; q++) { uu[q] = u[rr][q] + __shfl_xor(u[rr][q], 32); }
        float ls = lsum[rr];
#pragma unroll
        for (int off = 32; off; off >>= 1) ls += __shfl_xor(ls, off);
        const float inv = 1.f / ((float)NN + ls);

        bf16x8 hp = *(const bf16x8*)((const short*)hprev + (size_t)i * HH + 8 * sl);
        float x[8];
        float part = 0.f;
#pragma unroll
        for (int q = 0; q < 8; q++) { x[q] = bf2f(hp[q]) + (Sts[q] + uu[q]) * inv; part += x[q]; }
#pragma unroll
        for (int off = 16; off; off >>= 1) part += __shfl_xor(part, off);
        float mu = part * (1.f / HH);
        float d[8];
        float vs = 0.f;
#pragma unroll
        for (int q = 0; q < 8; q++) { d[q] = x[q] - mu; vs += d[q] * d[q]; }
#pragma unroll
        for (int off = 16; off; off >>= 1) vs += __shfl_xor(vs, off);
        float rstd = rsqrtf(vs * (1.f / HH) + LN_EPS);
        float y[8];
#pragma unroll
        for (int q = 0; q < 8; q++) {
            float t = d[q] * rstd * gg[q] + bv[q];
            y[q] = t > 0.f ? t : __expf(t) - 1.f;
        }

        if (houtb) {
            s16x4 yv;
#pragma unroll
            for (int q = 0; q < 4; q++) yv[q] = f2bf_bits(y[4 * half + q]);
            *(s16x4*)((short*)houtb + (size_t)i * HH + co) = yv;
        }
        if (houtf) {
            float4 yf = { y[4 * half], y[4 * half + 1], y[4 * half + 2], y[4 * half + 3] };
            *(float4*)(houtf + (size_t)i * HH + co) = yf;
        }
        if (last) {
            float p = 0.f;
#pragma unroll
            for (int q = 0; q < 8; q++) p += y[q] * wp[q];
#pragma unroll
            for (int off = 16; off; off >>= 1) p += __shfl_xor(p, off);
            if (lane == 0) gate[i] = 1.f / (1.f + __expf(-(p + bp)));
        }
    }
}

// ---------------- pooling: 256 blocks x 32 rows (256 atomics/address) ----------------
__global__ __launch_bounds__(256) void pool_kernel(const float* __restrict__ h, const float* __restrict__ gate,
                                                   float* __restrict__ emb) {
    int c = threadIdx.x;
    int r0 = blockIdx.x * 32;
    float acc = 0.f;
#pragma unroll
    for (int rr = 0; rr < 32; rr++) {
        int r = r0 + rr;
        acc += gate[r] * h[(size_t)r * HH + c];
    }
    atomicAdd(&emb[c], acc);
}

extern "C" void kernel_launch(void* const* d_in, const int* in_sizes, int n_in,
                              void* d_out, int out_size, void* d_ws, size_t ws_size,
                              hipStream_t stream) {
    const float* X      = (const float*)d_in[0];
    const int*   ei     = (const int*)d_in[1];
    const float* W_in   = (const float*)d_in[2];
    const float* b_in   = (const float*)d_in[3];
    const float* W_gat  = (const float*)d_in[4];
    const float* a_gat  = (const float*)d_in[5];
    const float* ln_g   = (const float*)d_in[6];
    const float* ln_b   = (const float*)d_in[7];
    const float* W_pool = (const float*)d_in[8];
    const float* b_pool = (const float*)d_in[9];
    float* out = (float*)d_out;

    // ws layout: bf16/fp8 region, then zero-init fp32/int block, then gate/buckets
    __hip_bfloat16* hb    = (__hip_bfloat16*)d_ws;            // NN*HH bf16
    uint8_t*        hw8   = (uint8_t*)(hb + (size_t)NN * HH); // NN*HH fp8
    __hip_bfloat16* Wb_in = (__hip_bfloat16*)(hw8 + (size_t)NN * HH); // HH*DIN
    __hip_bfloat16* Wgb   = Wb_in + (size_t)HH * DIN;         // 2*HH*HH
    __hip_bfloat16* Xb    = Wgb + (size_t)2 * HH * HH;        // NN*DIN
    float* zbase = (float*)(Xb + (size_t)NN * DIN);
    float* s1_0 = zbase;                 // NN
    float* s2_0 = s1_0 + NN;             // NN
    float* St_0 = s2_0 + NN;             // HH
    float* s1_1 = St_0 + HH;             // NN
    float* s2_1 = s1_1 + NN;             // NN
    float* St_1 = s2_1 + NN;             // HH
    int* cnt  = (int*)(St_1 + HH);       // NN  (zeroed in prep)
    float* gate = (float*)(cnt + NN);    // NN
    int* buck = (int*)(gate + NN);       // NN*CAP

    const int* src = ei;
    const int* tgt = ei + EE;
    float* emb = out + (size_t)NN * HH;

    // prep: zero + all bf16 conversions (one dispatch)
    int prep_quads = (NW1 + NW2 + NX) / 4;
    prep<<<(prep_quads + 255) / 256, 256, 0, stream>>>(W_in, Wb_in, W_gat, Wgb, X, Xb, zbase, emb);

    // adjacency buckets (one dispatch)
    fill_buckets<<<EE / 512, 256, 0, stream>>>(src, tgt, cnt, buck);

    // h = X @ W_in^T + b_in
    gemm_bb_bias<<<dim3(HH / 64, NN / 64), 256, 0, stream>>>(Xb, Wb_in, b_in, hb, HH, DIN);

    for (int ll = 0; ll < 2; ll++) {
        float* s1 = ll ? s1_1 : s1_0;
        float* s2 = ll ? s2_1 : s2_0;
        float* St = ll ? St_1 : St_0;
        const float* ag = a_gat + (size_t)ll * 2 * HH;
        gemm_bb_score<<<dim3(HH / 64, NN / 64), 256, 0, stream>>>(hb, Wgb + (size_t)ll * HH * HH, hw8,
                                                                  ag, ag + HH, s1, s2, St, HH, HH);
        gat_row<<<NN / 16, 256, 0, stream>>>(hb, hw8, cnt, buck, s1, s2, St,
                                             ln_g + (size_t)ll * HH, ln_b + (size_t)ll * HH,
                                             W_pool, b_pool,
                                             (ll == 1) ? out : nullptr,
                                             (ll == 0) ? hb : nullptr,
                                             gate, ll);
    }

    pool_kernel<<<NN / 32, 256, 0, stream>>>(out, gate, emb);
}